// Round 10
// baseline (45.507 us; speedup 1.0000x reference)
//
#include <hip/hip_runtime.h>
#include <math.h>

#define N_PED 768
#define NW 12  // 768/64 u64 words per adjacency column

// ---------------- ws layout (bytes) ----------------
// adjT16  : [768*48] u16  @ 0       (73728)  column-major bits, 16-bit row-chunks
//           u64 view: word (c, I) at adjT[c*12+I]
// rowmaxT : [12][768] int @ 73728   (36864)  per-tile row max col (or -1)
// idx     : [768] int     @ 110592  (3072)   -> ends 113664

// KB: fused per-node features + pairwise dist + bit-transpose.
// Block = (tile I,J; row-chunk of 16 rows). Upper tiles (I<J) structurally
// zero: fill and exit. Compute blocks: recompute A (f64, exact reference
// ordering) for the 64 col nodes + 16 row nodes in LDS, then 4 waves x 4 rows
// of 64-lane pair evaluation -> ballot words -> u16 transpose store.
__global__ __launch_bounds__(256) void kb(
    const float* __restrict__ va, const float* __restrict__ vr,
    const float* __restrict__ velw, const float* __restrict__ velb,
    const float* __restrict__ g1w, const float* __restrict__ g1b,
    const float* __restrict__ gam, const float* __restrict__ bet,
    const float* __restrict__ g2w, const float* __restrict__ g2b,
    unsigned short* __restrict__ adjT16, int* __restrict__ rowmaxT) {
  int bid = blockIdx.x;
  int tile = bid >> 2, chunk = bid & 3;
  int I = tile / NW, J = tile % NW;
  int tid = threadIdx.x;
  if (I < J) {  // structurally zero
    if (tid < 64) adjT16[(J * 64 + tid) * 48 + I * 4 + chunk] = 0;
    if (tid < 16) rowmaxT[J * N_PED + I * 64 + chunk * 16 + tid] = -1;
    return;
  }
  __shared__ double Acol[16][64];
  __shared__ double Arow[16][16];
  __shared__ unsigned long long roww[16];

  // ---- A compute: jobs 0..63 col nodes, 64..79 row nodes; 2 threads/job ----
  {
    int job = tid >> 1, half = tid & 1;
    bool isrow = (job >= 64);
    bool active = (job < 80) && !(isrow && I == J);
    if (active) {
      int node = isrow ? (I * 64 + chunk * 16 + (job - 64)) : (J * 64 + job);
      double F[32];
#pragma unroll
      for (int cc = 0; cc < 2; ++cc)
#pragma unroll
        for (int t = 0; t < 8; ++t)
          F[cc * 8 + t] = (double)va[(cc * 8 + t) * N_PED + node];
#pragma unroll
      for (int o = 0; o < 2; ++o)
#pragma unroll
        for (int t = 0; t < 8; ++t)
          F[(2 + o) * 8 + t] = (double)velb[o]
              + (double)velw[o * 2 + 0] * (double)vr[(0 + t) * N_PED + node]
              + (double)velw[o * 2 + 1] * (double)vr[(8 + t) * N_PED + node];
      for (int o = half * 8; o < half * 8 + 8; ++o) {
        double s = 0.0;
#pragma unroll
        for (int k = 0; k < 32; ++k) s += (double)g1w[o * 32 + k] * F[k];
        if (isrow) Arow[o][job - 64] = s;
        else Acol[o][job] = s;
      }
    }
  }
  __syncthreads();

  // ---- effective MLP params (uniform, exact reference ordering) ----
  double w2[16], b1[16];
  const double inv_std = 1.0 / sqrt(1.0 + 1e-5);
#pragma unroll
  for (int o = 0; o < 16; ++o) {
    w2[o] = (double)g2w[o] * inv_std * (double)gam[o];
    b1[o] = (double)g1b[o];
  }
  double c0 = (double)g2b[0];
#pragma unroll
  for (int o = 0; o < 16; ++o) c0 += (double)g2w[o] * (double)bet[o];

  int w = tid >> 6, lane = tid & 63;
  int c = J * 64 + lane;
  double Ac[16];
#pragma unroll
  for (int o = 0; o < 16; ++o) Ac[o] = Acol[o][lane];

  for (int q = 0; q < 4; ++q) {
    int rr = w * 4 + q;
    int r = I * 64 + chunk * 16 + rr;
    double x1 = 0.0, x2 = 0.0;
#pragma unroll
    for (int o = 0; o < 16; ++o) {
      double Av = (I == J) ? Acol[o][chunk * 16 + rr] : Arow[o][rr];
      double s = Av - Ac[o];
      x1 += w2[o] * fmax(s + b1[o], 0.0);
      x2 += w2[o] * fmax(b1[o] - s, 0.0);
    }
    double dist = 0.5 * (exp(x1 + c0) + exp(x2 + c0));
    bool bit = (c < r) && (dist <= 1.0);
    unsigned long long word = __ballot(bit ? 1 : 0);
    if (lane == 0) {
      roww[rr] = word;
      rowmaxT[J * N_PED + r] =
          word ? (J * 64 + 63 - __clzll((long long)word)) : -1;
    }
  }
  __syncthreads();

  if (tid < 64) {  // transpose 16 rows x 64 cols -> u16 per col
    unsigned m = 0;
#pragma unroll
    for (int rr = 0; rr < 16; ++rr)
      m |= (unsigned)((roww[rr] >> tid) & 1ull) << rr;
    adjT16[(J * 64 + tid) * 48 + I * 4 + chunk] = (unsigned short)m;
  }
}

// K3: pointer-doubling over the successor forest (proved R4):
//   v0[n]   = rowcm[n] >= 0 ? rowcm[n] : n
//   succ(n) = first set bit in column v0[n] strictly below row n (self if none)
//   label(n) = v0 at root; labels ranked ascending -> group ids.
__global__ __launch_bounds__(768) void k3s(
    const unsigned long long* __restrict__ adjT,
    const int* __restrict__ rowmaxT, int* __restrict__ out_idx) {
  __shared__ int nxtA[N_PED], nxtB[N_PED];
  __shared__ int valL[N_PED], labL[N_PED], rankL[N_PED];
  const int n = threadIdx.x;

  int cm = -1;
#pragma unroll
  for (int j = 0; j < NW; ++j) {
    int t = rowmaxT[j * N_PED + n];
    cm = t > cm ? t : cm;
  }
  int v0 = (cm >= 0) ? cm : n;
  valL[n] = v0;

  int succ = n;
  {
    int j = n >> 6, rl = n & 63;
    unsigned long long w0 = (adjT[v0 * NW + j] >> rl) >> 1;
    if (w0) {
      succ = n + __ffsll(w0);
    } else {
      for (++j; j < NW; ++j) {
        unsigned long long ww = adjT[v0 * NW + j];
        if (ww) { succ = j * 64 + __ffsll(ww) - 1; break; }
      }
    }
  }
  nxtA[n] = succ;
  __syncthreads();

  int* src = nxtA;
  int* dst = nxtB;
#pragma unroll
  for (int it = 0; it < 10; ++it) {  // 2^10 >= 767
    dst[n] = src[src[n]];
    __syncthreads();
    int* t = src; src = dst; dst = t;
  }
  labL[n] = valL[src[n]];
  __syncthreads();

  nxtA[n] = 0;  // reuse as flags
  __syncthreads();
  nxtA[labL[n]] = 1;
  __syncthreads();
  if (n < 64) {  // wave 0: 12-segment scan ranks distinct labels ascending
    int f[NW], s = 0;
#pragma unroll
    for (int q = 0; q < NW; ++q) { f[q] = nxtA[n * NW + q]; s += f[q]; }
    int inc = s;
    for (int d = 1; d < 64; d <<= 1) {
      int t = __shfl_up(inc, d);
      if (n >= d) inc += t;
    }
    int run = inc - s;
#pragma unroll
    for (int q = 0; q < NW; ++q) { run += f[q]; rankL[n * NW + q] = run - 1; }
  }
  __syncthreads();
  out_idx[n] = rankL[labL[n]];
}

// K45: fused pooling + epilogue, one wave per node n.
// Lanes scan all 768 nodes (12 strided iters), predicated-accumulate the 16
// channels of members of group g(n) (coalesced, independent loads), butterfly
// shfl_xor reduce (sum order identical to the R8 k4), then lanes 0..59 each
// produce one (o,p) output for n (expression order identical to R8 k5).
__global__ __launch_bounds__(256) void k45(
    const float* __restrict__ vrel, const int* __restrict__ idx,
    const float* __restrict__ wt, const float* __restrict__ wc,
    float* __restrict__ out) {
  int n = blockIdx.x * 4 + (threadIdx.x >> 6);  // node id, 0..767
  int lane = threadIdx.x & 63;
  int g = idx[n];  // uniform per wave

  float s[16];
#pragma unroll
  for (int ct = 0; ct < 16; ++ct) s[ct] = 0.f;
  int cnt = 0;
#pragma unroll
  for (int k = 0; k < NW; ++k) {
    int m = k * 64 + lane;
    bool mem = (idx[m] == g);
    cnt += mem ? 1 : 0;
#pragma unroll
    for (int ct = 0; ct < 16; ++ct) {
      float v = vrel[ct * N_PED + m];
      s[ct] += mem ? v : 0.f;
    }
  }
#pragma unroll
  for (int d = 1; d < 64; d <<= 1) {
    cnt += __shfl_xor(cnt, d);
#pragma unroll
    for (int ct = 0; ct < 16; ++ct) s[ct] += __shfl_xor(s[ct], d);
  }
  float cmax = fmaxf((float)cnt, 1.0f);
  float pool[16];
#pragma unroll
  for (int ct = 0; ct < 16; ++ct) pool[ct] = s[ct] / cmax;

  if (lane < 60) {
    int o = lane / 12, p = lane % 12;
    float v1 = 0.f, v2 = 0.f;
#pragma unroll
    for (int c = 0; c < 2; ++c) {
      float u1 = 0.f, u2 = 0.f;
#pragma unroll
      for (int t = 0; t < 8; ++t) {
        float wtv = wt[t * 12 + p];
        u1 += wtv * vrel[(c * 8 + t) * N_PED + n];
        u2 += wtv * pool[c * 8 + t];
      }
      float wcv = wc[c * 5 + o];
      v1 += wcv * u1;
      v2 += wcv * u2;
    }
    out[(o * 12 + p) * N_PED + n] = (v1 + v2 + v1) / 3.0f;
  }
}

extern "C" void kernel_launch(void* const* d_in, const int* in_sizes, int n_in,
                              void* d_out, int out_size, void* d_ws, size_t ws_size,
                              hipStream_t stream) {
  const float* va   = (const float*)d_in[0];
  const float* vr   = (const float*)d_in[1];
  const float* velw = (const float*)d_in[2];
  const float* velb = (const float*)d_in[3];
  const float* g1w  = (const float*)d_in[4];
  const float* g1b  = (const float*)d_in[5];
  const float* gam  = (const float*)d_in[6];
  const float* bet  = (const float*)d_in[7];
  const float* g2w  = (const float*)d_in[8];
  const float* g2b  = (const float*)d_in[9];
  const float* wt   = (const float*)d_in[10];
  const float* wc   = (const float*)d_in[11];
  float* out = (float*)d_out;

  char* ws = (char*)d_ws;
  unsigned short* adjT16 = (unsigned short*)(ws + 0);
  unsigned long long* adjT = (unsigned long long*)(ws + 0);
  int* rowmaxT = (int*)(ws + 73728);
  int* idx = (int*)(ws + 110592);

  kb<<<576, 256, 0, stream>>>(va, vr, velw, velb, g1w, g1b, gam, bet, g2w, g2b,
                              adjT16, rowmaxT);
  k3s<<<1, 768, 0, stream>>>(adjT, rowmaxT, idx);
  k45<<<192, 256, 0, stream>>>(vr, idx, wt, wc, out);
}

// Round 11
// 31.287 us; speedup vs baseline: 1.4545x; 1.4545x over previous
//
#include <hip/hip_runtime.h>
#include <math.h>

#define N_PED 768
#define NW 12  // 768/64 u64 words per adjacency column

// ---------------- ws layout (bytes) ----------------
// adjT16  : [768*48] u16  @ 0       (73728)  column-major bits, 16-bit row-chunks
//           u64 view: word (c, I) at adjT[c*12+I]
// rowmaxT : [12][768] int @ 73728   (36864)  per-tile row max col (or -1)
// idx     : [768] int     @ 110592  (3072)   -> ends 113664

// KB: fused per-node features + pairwise dist + bit-transpose.
// Block = (tile I,J; row-chunk of 16 rows). Upper tiles (I<J) structurally
// zero: fill and exit. Compute blocks: recompute A (f64, exact reference
// ordering) for the 64 col nodes + 16 row nodes in LDS, then 4 waves x 4 rows
// of 64-lane pair evaluation -> ballot words -> u16 transpose store.
__global__ __launch_bounds__(256) void kb(
    const float* __restrict__ va, const float* __restrict__ vr,
    const float* __restrict__ velw, const float* __restrict__ velb,
    const float* __restrict__ g1w, const float* __restrict__ g1b,
    const float* __restrict__ gam, const float* __restrict__ bet,
    const float* __restrict__ g2w, const float* __restrict__ g2b,
    unsigned short* __restrict__ adjT16, int* __restrict__ rowmaxT) {
  int bid = blockIdx.x;
  int tile = bid >> 2, chunk = bid & 3;
  int I = tile / NW, J = tile % NW;
  int tid = threadIdx.x;
  if (I < J) {  // structurally zero
    if (tid < 64) adjT16[(J * 64 + tid) * 48 + I * 4 + chunk] = 0;
    if (tid < 16) rowmaxT[J * N_PED + I * 64 + chunk * 16 + tid] = -1;
    return;
  }
  __shared__ double Acol[16][64];
  __shared__ double Arow[16][16];
  __shared__ unsigned long long roww[16];

  // ---- A compute: jobs 0..63 col nodes, 64..79 row nodes; 2 threads/job ----
  {
    int job = tid >> 1, half = tid & 1;
    bool isrow = (job >= 64);
    bool active = (job < 80) && !(isrow && I == J);
    if (active) {
      int node = isrow ? (I * 64 + chunk * 16 + (job - 64)) : (J * 64 + job);
      double F[32];
#pragma unroll
      for (int cc = 0; cc < 2; ++cc)
#pragma unroll
        for (int t = 0; t < 8; ++t)
          F[cc * 8 + t] = (double)va[(cc * 8 + t) * N_PED + node];
#pragma unroll
      for (int o = 0; o < 2; ++o)
#pragma unroll
        for (int t = 0; t < 8; ++t)
          F[(2 + o) * 8 + t] = (double)velb[o]
              + (double)velw[o * 2 + 0] * (double)vr[(0 + t) * N_PED + node]
              + (double)velw[o * 2 + 1] * (double)vr[(8 + t) * N_PED + node];
      for (int o = half * 8; o < half * 8 + 8; ++o) {
        double s = 0.0;
#pragma unroll
        for (int k = 0; k < 32; ++k) s += (double)g1w[o * 32 + k] * F[k];
        if (isrow) Arow[o][job - 64] = s;
        else Acol[o][job] = s;
      }
    }
  }
  __syncthreads();

  // ---- effective MLP params (uniform, exact reference ordering) ----
  double w2[16], b1[16];
  const double inv_std = 1.0 / sqrt(1.0 + 1e-5);
#pragma unroll
  for (int o = 0; o < 16; ++o) {
    w2[o] = (double)g2w[o] * inv_std * (double)gam[o];
    b1[o] = (double)g1b[o];
  }
  double c0 = (double)g2b[0];
#pragma unroll
  for (int o = 0; o < 16; ++o) c0 += (double)g2w[o] * (double)bet[o];

  int w = tid >> 6, lane = tid & 63;
  int c = J * 64 + lane;
  double Ac[16];
#pragma unroll
  for (int o = 0; o < 16; ++o) Ac[o] = Acol[o][lane];

  for (int q = 0; q < 4; ++q) {
    int rr = w * 4 + q;
    int r = I * 64 + chunk * 16 + rr;
    double x1 = 0.0, x2 = 0.0;
#pragma unroll
    for (int o = 0; o < 16; ++o) {
      double Av = (I == J) ? Acol[o][chunk * 16 + rr] : Arow[o][rr];
      double s = Av - Ac[o];
      x1 += w2[o] * fmax(s + b1[o], 0.0);
      x2 += w2[o] * fmax(b1[o] - s, 0.0);
    }
    double dist = 0.5 * (exp(x1 + c0) + exp(x2 + c0));
    bool bit = (c < r) && (dist <= 1.0);
    unsigned long long word = __ballot(bit ? 1 : 0);
    if (lane == 0) {
      roww[rr] = word;
      rowmaxT[J * N_PED + r] =
          word ? (J * 64 + 63 - __clzll((long long)word)) : -1;
    }
  }
  __syncthreads();

  if (tid < 64) {  // transpose 16 rows x 64 cols -> u16 per col
    unsigned m = 0;
#pragma unroll
    for (int rr = 0; rr < 16; ++rr)
      m |= (unsigned)((roww[rr] >> tid) & 1ull) << rr;
    adjT16[(J * 64 + tid) * 48 + I * 4 + chunk] = (unsigned short)m;
  }
}

// K3: pointer-doubling over the successor forest (proved R4):
//   v0[n]   = rowcm[n] >= 0 ? rowcm[n] : n
//   succ(n) = first set bit in column v0[n] strictly below row n (self if none)
//   label(n) = v0 at root; labels ranked ascending -> group ids.
__global__ __launch_bounds__(768) void k3s(
    const unsigned long long* __restrict__ adjT,
    const int* __restrict__ rowmaxT, int* __restrict__ out_idx) {
  __shared__ int nxtA[N_PED], nxtB[N_PED];
  __shared__ int valL[N_PED], labL[N_PED], rankL[N_PED];
  const int n = threadIdx.x;

  int cm = -1;
#pragma unroll
  for (int j = 0; j < NW; ++j) {
    int t = rowmaxT[j * N_PED + n];
    cm = t > cm ? t : cm;
  }
  int v0 = (cm >= 0) ? cm : n;
  valL[n] = v0;

  int succ = n;
  {
    int j = n >> 6, rl = n & 63;
    unsigned long long w0 = (adjT[v0 * NW + j] >> rl) >> 1;
    if (w0) {
      succ = n + __ffsll(w0);
    } else {
      for (++j; j < NW; ++j) {
        unsigned long long ww = adjT[v0 * NW + j];
        if (ww) { succ = j * 64 + __ffsll(ww) - 1; break; }
      }
    }
  }
  nxtA[n] = succ;
  __syncthreads();

  int* src = nxtA;
  int* dst = nxtB;
#pragma unroll
  for (int it = 0; it < 10; ++it) {  // 2^10 >= 767
    dst[n] = src[src[n]];
    __syncthreads();
    int* t = src; src = dst; dst = t;
  }
  labL[n] = valL[src[n]];
  __syncthreads();

  nxtA[n] = 0;  // reuse as flags
  __syncthreads();
  nxtA[labL[n]] = 1;
  __syncthreads();
  if (n < 64) {  // wave 0: 12-segment scan ranks distinct labels ascending
    int f[NW], s = 0;
#pragma unroll
    for (int q = 0; q < NW; ++q) { f[q] = nxtA[n * NW + q]; s += f[q]; }
    int inc = s;
    for (int d = 1; d < 64; d <<= 1) {
      int t = __shfl_up(inc, d);
      if (n >= d) inc += t;
    }
    int run = inc - s;
#pragma unroll
    for (int q = 0; q < NW; ++q) { run += f[q]; rankL[n * NW + q] = run - 1; }
  }
  __syncthreads();
  out_idx[n] = rankL[labL[n]];
}

// K45: fused pooling + epilogue, one BLOCK per node n (768 blocks, 4 waves).
// 256 threads split the 768-node membership scan (3 nodes/thread, 51
// independent coalesced loads), butterfly-reduce 17 values within each wave,
// combine the 4 wave-partials through LDS, then wave 0 lanes 0..59 emit the
// 60 outputs of node n. Sum order: lane-partial -> wave butterfly -> 4-way
// partial add (reassociation well under threshold).
__global__ __launch_bounds__(256) void k45(
    const float* __restrict__ vrel, const int* __restrict__ idx,
    const float* __restrict__ wt, const float* __restrict__ wc,
    float* __restrict__ out) {
  __shared__ float part[4][17];
  const int n = blockIdx.x;
  const int tid = threadIdx.x;
  const int w = tid >> 6, lane = tid & 63;
  const int g = idx[n];  // uniform across block

  float s[16];
#pragma unroll
  for (int ct = 0; ct < 16; ++ct) s[ct] = 0.f;
  int cnt = 0;
#pragma unroll
  for (int q = 0; q < 3; ++q) {
    int m = q * 256 + tid;
    bool mem = (idx[m] == g);
    cnt += mem ? 1 : 0;
#pragma unroll
    for (int ct = 0; ct < 16; ++ct) {
      float v = vrel[ct * N_PED + m];
      s[ct] += mem ? v : 0.f;
    }
  }
#pragma unroll
  for (int d = 1; d < 64; d <<= 1) {
    cnt += __shfl_xor(cnt, d);
#pragma unroll
    for (int ct = 0; ct < 16; ++ct) s[ct] += __shfl_xor(s[ct], d);
  }
  if (lane == 0) {
#pragma unroll
    for (int ct = 0; ct < 16; ++ct) part[w][ct] = s[ct];
    part[w][16] = (float)cnt;
  }
  __syncthreads();

  if (w == 0) {
    float pool[16];
    float cntf = part[0][16] + part[1][16] + part[2][16] + part[3][16];
    float cmax = fmaxf(cntf, 1.0f);
#pragma unroll
    for (int ct = 0; ct < 16; ++ct)
      pool[ct] = (part[0][ct] + part[1][ct] + part[2][ct] + part[3][ct]) / cmax;

    if (lane < 60) {
      int o = lane / 12, p = lane % 12;
      float v1 = 0.f, v2 = 0.f;
#pragma unroll
      for (int c = 0; c < 2; ++c) {
        float u1 = 0.f, u2 = 0.f;
#pragma unroll
        for (int t = 0; t < 8; ++t) {
          float wtv = wt[t * 12 + p];
          u1 += wtv * vrel[(c * 8 + t) * N_PED + n];
          u2 += wtv * pool[c * 8 + t];
        }
        float wcv = wc[c * 5 + o];
        v1 += wcv * u1;
        v2 += wcv * u2;
      }
      out[(o * 12 + p) * N_PED + n] = (v1 + v2 + v1) / 3.0f;
    }
  }
}

extern "C" void kernel_launch(void* const* d_in, const int* in_sizes, int n_in,
                              void* d_out, int out_size, void* d_ws, size_t ws_size,
                              hipStream_t stream) {
  const float* va   = (const float*)d_in[0];
  const float* vr   = (const float*)d_in[1];
  const float* velw = (const float*)d_in[2];
  const float* velb = (const float*)d_in[3];
  const float* g1w  = (const float*)d_in[4];
  const float* g1b  = (const float*)d_in[5];
  const float* gam  = (const float*)d_in[6];
  const float* bet  = (const float*)d_in[7];
  const float* g2w  = (const float*)d_in[8];
  const float* g2b  = (const float*)d_in[9];
  const float* wt   = (const float*)d_in[10];
  const float* wc   = (const float*)d_in[11];
  float* out = (float*)d_out;

  char* ws = (char*)d_ws;
  unsigned short* adjT16 = (unsigned short*)(ws + 0);
  unsigned long long* adjT = (unsigned long long*)(ws + 0);
  int* rowmaxT = (int*)(ws + 73728);
  int* idx = (int*)(ws + 110592);

  kb<<<576, 256, 0, stream>>>(va, vr, velw, velb, g1w, g1b, gam, bet, g2w, g2b,
                              adjT16, rowmaxT);
  k3s<<<1, 768, 0, stream>>>(adjT, rowmaxT, idx);
  k45<<<768, 256, 0, stream>>>(vr, idx, wt, wc, out);
}

// Round 12
// 31.239 us; speedup vs baseline: 1.4568x; 1.0015x over previous
//
#include <hip/hip_runtime.h>
#include <math.h>

#define N_PED 768
#define NW 12  // 768/64 u64 words per adjacency column

// ---------------- ws layout (bytes) ----------------
// adjT16  : [768*48] u16  @ 0       (73728)  column-major bits, 16-bit row-chunks
//           u64 view: word (c, I) at adjT[c*12+I]; upper tiles (I<J) unwritten
//           (proved unread: succ scan only touches words I >= J)
// rowmaxT : [12][768] int @ 73728   (36864)  per-tile row max col (or -1)

// KB: fused per-node features + pairwise dist + bit-transpose.
// Block = (tile I,J; row-chunk of 16 rows). Upper tiles (I<J): only the
// rowmaxT = -1 fills are needed. Compute blocks: recompute A (f64, exact
// reference ordering) for the 64 col + 16 row nodes in LDS, then 4 waves x
// 4 rows of 64-lane pair evaluation -> ballot words -> u16 transpose store.
__global__ __launch_bounds__(256) void kb(
    const float* __restrict__ va, const float* __restrict__ vr,
    const float* __restrict__ velw, const float* __restrict__ velb,
    const float* __restrict__ g1w, const float* __restrict__ g1b,
    const float* __restrict__ gam, const float* __restrict__ bet,
    const float* __restrict__ g2w, const float* __restrict__ g2b,
    unsigned short* __restrict__ adjT16, int* __restrict__ rowmaxT) {
  int bid = blockIdx.x;
  int tile = bid >> 2, chunk = bid & 3;
  int I = tile / NW, J = tile % NW;
  int tid = threadIdx.x;
  if (I < J) {  // structurally zero; adjT words here are never read
    if (tid < 16) rowmaxT[J * N_PED + I * 64 + chunk * 16 + tid] = -1;
    return;
  }
  __shared__ double Acol[16][64];
  __shared__ double Arow[16][16];
  __shared__ unsigned long long roww[16];

  // ---- A compute: jobs 0..63 col nodes, 64..79 row nodes; 2 threads/job ----
  {
    int job = tid >> 1, half = tid & 1;
    bool isrow = (job >= 64);
    bool active = (job < 80) && !(isrow && I == J);
    if (active) {
      int node = isrow ? (I * 64 + chunk * 16 + (job - 64)) : (J * 64 + job);
      double F[32];
#pragma unroll
      for (int cc = 0; cc < 2; ++cc)
#pragma unroll
        for (int t = 0; t < 8; ++t)
          F[cc * 8 + t] = (double)va[(cc * 8 + t) * N_PED + node];
#pragma unroll
      for (int o = 0; o < 2; ++o)
#pragma unroll
        for (int t = 0; t < 8; ++t)
          F[(2 + o) * 8 + t] = (double)velb[o]
              + (double)velw[o * 2 + 0] * (double)vr[(0 + t) * N_PED + node]
              + (double)velw[o * 2 + 1] * (double)vr[(8 + t) * N_PED + node];
      for (int o = half * 8; o < half * 8 + 8; ++o) {
        double s = 0.0;
#pragma unroll
        for (int k = 0; k < 32; ++k) s += (double)g1w[o * 32 + k] * F[k];
        if (isrow) Arow[o][job - 64] = s;
        else Acol[o][job] = s;
      }
    }
  }
  __syncthreads();

  // ---- effective MLP params (uniform, exact reference ordering) ----
  double w2[16], b1[16];
  const double inv_std = 1.0 / sqrt(1.0 + 1e-5);
#pragma unroll
  for (int o = 0; o < 16; ++o) {
    w2[o] = (double)g2w[o] * inv_std * (double)gam[o];
    b1[o] = (double)g1b[o];
  }
  double c0 = (double)g2b[0];
#pragma unroll
  for (int o = 0; o < 16; ++o) c0 += (double)g2w[o] * (double)bet[o];

  int w = tid >> 6, lane = tid & 63;
  int c = J * 64 + lane;
  double Ac[16];
#pragma unroll
  for (int o = 0; o < 16; ++o) Ac[o] = Acol[o][lane];

  for (int q = 0; q < 4; ++q) {
    int rr = w * 4 + q;
    int r = I * 64 + chunk * 16 + rr;
    double x1 = 0.0, x2 = 0.0;
#pragma unroll
    for (int o = 0; o < 16; ++o) {
      double Av = (I == J) ? Acol[o][chunk * 16 + rr] : Arow[o][rr];
      double s = Av - Ac[o];
      x1 += w2[o] * fmax(s + b1[o], 0.0);
      x2 += w2[o] * fmax(b1[o] - s, 0.0);
    }
    double dist = 0.5 * (exp(x1 + c0) + exp(x2 + c0));
    bool bit = (c < r) && (dist <= 1.0);
    unsigned long long word = __ballot(bit ? 1 : 0);
    if (lane == 0) {
      roww[rr] = word;
      rowmaxT[J * N_PED + r] =
          word ? (J * 64 + 63 - __clzll((long long)word)) : -1;
    }
  }
  __syncthreads();

  if (tid < 64) {  // transpose 16 rows x 64 cols -> u16 per col
    unsigned m = 0;
#pragma unroll
    for (int rr = 0; rr < 16; ++rr)
      m |= (unsigned)((roww[rr] >> tid) & 1ull) << rr;
    adjT16[(J * 64 + tid) * 48 + I * 4 + chunk] = (unsigned short)m;
  }
}

// K345: fused grouping + pooling + epilogue. One BLOCK per node n (768
// blocks, 256 threads). Each block redundantly computes the full label array
// (rank step dropped — pooling only needs membership lab[m]==lab[n], and the
// reference's rank mapping cancels between pool-build and gather):
//   v0[m]   = rowcm[m] >= 0 ? rowcm[m] : m
//   succ(m) = first set bit in column v0[m] strictly below row m (self if none)
//   lab(m)  = v0 at the forest root, via 10 pointer-jump rounds in LDS.
// Then pooling/epilogue exactly as R10's k45 (same accumulation order).
__global__ __launch_bounds__(256) void k345(
    const unsigned long long* __restrict__ adjT,
    const int* __restrict__ rowmaxT, const float* __restrict__ vrel,
    const float* __restrict__ wt, const float* __restrict__ wc,
    float* __restrict__ out) {
  __shared__ int nxtA[N_PED], nxtB[N_PED], valL[N_PED], labL[N_PED];
  __shared__ float part[4][17];
  const int n = blockIdx.x;
  const int tid = threadIdx.x;
  const int w = tid >> 6, lane = tid & 63;

  // --- labels (redundant per block) ---
#pragma unroll
  for (int q = 0; q < 3; ++q) {
    int m = q * 256 + tid;
    int cm = -1;
#pragma unroll
    for (int j = 0; j < NW; ++j) {
      int t = rowmaxT[j * N_PED + m];
      cm = t > cm ? t : cm;
    }
    int v0 = (cm >= 0) ? cm : m;
    valL[m] = v0;
    int succ = m;
    int j = m >> 6, rl = m & 63;
    unsigned long long w0 = (adjT[v0 * NW + j] >> rl) >> 1;
    if (w0) {
      succ = m + __ffsll(w0);
    } else {
      for (++j; j < NW; ++j) {
        unsigned long long ww = adjT[v0 * NW + j];
        if (ww) { succ = j * 64 + __ffsll(ww) - 1; break; }
      }
    }
    nxtA[m] = succ;
  }
  __syncthreads();

  int* src = nxtA;
  int* dst = nxtB;
#pragma unroll
  for (int it = 0; it < 10; ++it) {  // 2^10 >= 767
#pragma unroll
    for (int q = 0; q < 3; ++q) {
      int m = q * 256 + tid;
      dst[m] = src[src[m]];
    }
    __syncthreads();
    int* t = src; src = dst; dst = t;
  }
#pragma unroll
  for (int q = 0; q < 3; ++q) {
    int m = q * 256 + tid;
    labL[m] = valL[src[m]];
  }
  __syncthreads();

  const int gl = labL[n];  // this block's group label (uniform)

  // --- pooling: 3 nodes/thread, wave butterfly, 4-way LDS combine ---
  float s[16];
#pragma unroll
  for (int ct = 0; ct < 16; ++ct) s[ct] = 0.f;
  int cnt = 0;
#pragma unroll
  for (int q = 0; q < 3; ++q) {
    int m = q * 256 + tid;
    bool mem = (labL[m] == gl);
    cnt += mem ? 1 : 0;
#pragma unroll
    for (int ct = 0; ct < 16; ++ct) {
      float v = vrel[ct * N_PED + m];
      s[ct] += mem ? v : 0.f;
    }
  }
#pragma unroll
  for (int d = 1; d < 64; d <<= 1) {
    cnt += __shfl_xor(cnt, d);
#pragma unroll
    for (int ct = 0; ct < 16; ++ct) s[ct] += __shfl_xor(s[ct], d);
  }
  if (lane == 0) {
#pragma unroll
    for (int ct = 0; ct < 16; ++ct) part[w][ct] = s[ct];
    part[w][16] = (float)cnt;
  }
  __syncthreads();

  // --- epilogue: wave 0, lanes 0..59 emit the 60 outputs of node n ---
  if (w == 0) {
    float pool[16];
    float cntf = part[0][16] + part[1][16] + part[2][16] + part[3][16];
    float cmax = fmaxf(cntf, 1.0f);
#pragma unroll
    for (int ct = 0; ct < 16; ++ct)
      pool[ct] = (part[0][ct] + part[1][ct] + part[2][ct] + part[3][ct]) / cmax;

    if (lane < 60) {
      int o = lane / 12, p = lane % 12;
      float v1 = 0.f, v2 = 0.f;
#pragma unroll
      for (int c = 0; c < 2; ++c) {
        float u1 = 0.f, u2 = 0.f;
#pragma unroll
        for (int t = 0; t < 8; ++t) {
          float wtv = wt[t * 12 + p];
          u1 += wtv * vrel[(c * 8 + t) * N_PED + n];
          u2 += wtv * pool[c * 8 + t];
        }
        float wcv = wc[c * 5 + o];
        v1 += wcv * u1;
        v2 += wcv * u2;
      }
      out[(o * 12 + p) * N_PED + n] = (v1 + v2 + v1) / 3.0f;
    }
  }
}

extern "C" void kernel_launch(void* const* d_in, const int* in_sizes, int n_in,
                              void* d_out, int out_size, void* d_ws, size_t ws_size,
                              hipStream_t stream) {
  const float* va   = (const float*)d_in[0];
  const float* vr   = (const float*)d_in[1];
  const float* velw = (const float*)d_in[2];
  const float* velb = (const float*)d_in[3];
  const float* g1w  = (const float*)d_in[4];
  const float* g1b  = (const float*)d_in[5];
  const float* gam  = (const float*)d_in[6];
  const float* bet  = (const float*)d_in[7];
  const float* g2w  = (const float*)d_in[8];
  const float* g2b  = (const float*)d_in[9];
  const float* wt   = (const float*)d_in[10];
  const float* wc   = (const float*)d_in[11];
  float* out = (float*)d_out;

  char* ws = (char*)d_ws;
  unsigned short* adjT16 = (unsigned short*)(ws + 0);
  unsigned long long* adjT = (unsigned long long*)(ws + 0);
  int* rowmaxT = (int*)(ws + 73728);

  kb<<<576, 256, 0, stream>>>(va, vr, velw, velb, g1w, g1b, gam, bet, g2w, g2b,
                              adjT16, rowmaxT);
  k345<<<768, 256, 0, stream>>>(adjT, rowmaxT, vr, wt, wc, out);
}

// Round 13
// 25.243 us; speedup vs baseline: 1.8027x; 1.2375x over previous
//
#include <hip/hip_runtime.h>
#include <math.h>

#define N_PED 768
#define NW 12  // 768/64 u64 words per adjacency column

// ---------------- ws layout (bytes) ----------------
// adjT16  : [768*48] u16  @ 0       (73728)  column-major bits, 16-bit row-chunks
//           u64 view: word (c, I) at adjT[c*12+I]; upper tiles (I<J) unwritten
//           (proved unread: succ scan only touches words I >= J)
// rowmaxT : [12][768] int @ 73728   (36864)  per-tile row max col (or -1)

// KB: fused per-node features + pairwise dist + bit-transpose.
// Block = (tile I,J; row-chunk of 16 rows). Upper tiles (I<J): only the
// rowmaxT = -1 fills are needed. Compute blocks: recompute A (f64, exact
// reference ordering) for the 64 col + 16 row nodes in LDS, then 4 waves x
// 4 rows of pair evaluation. NEW: all 8 dot-products computed first, then the
// 8 f64 exps issued back-to-back (independent -> ILP covers exp latency at
// ~1.2 waves/SIMD occupancy), then 4 ballots.
__global__ __launch_bounds__(256) void kb(
    const float* __restrict__ va, const float* __restrict__ vr,
    const float* __restrict__ velw, const float* __restrict__ velb,
    const float* __restrict__ g1w, const float* __restrict__ g1b,
    const float* __restrict__ gam, const float* __restrict__ bet,
    const float* __restrict__ g2w, const float* __restrict__ g2b,
    unsigned short* __restrict__ adjT16, int* __restrict__ rowmaxT) {
  int bid = blockIdx.x;
  int tile = bid >> 2, chunk = bid & 3;
  int I = tile / NW, J = tile % NW;
  int tid = threadIdx.x;
  if (I < J) {  // structurally zero; adjT words here are never read
    if (tid < 16) rowmaxT[J * N_PED + I * 64 + chunk * 16 + tid] = -1;
    return;
  }
  __shared__ double Acol[16][64];
  __shared__ double Arow[16][16];
  __shared__ unsigned long long roww[16];

  // ---- A compute: jobs 0..63 col nodes, 64..79 row nodes; 2 threads/job ----
  {
    int job = tid >> 1, half = tid & 1;
    bool isrow = (job >= 64);
    bool active = (job < 80) && !(isrow && I == J);
    if (active) {
      int node = isrow ? (I * 64 + chunk * 16 + (job - 64)) : (J * 64 + job);
      double F[32];
#pragma unroll
      for (int cc = 0; cc < 2; ++cc)
#pragma unroll
        for (int t = 0; t < 8; ++t)
          F[cc * 8 + t] = (double)va[(cc * 8 + t) * N_PED + node];
#pragma unroll
      for (int o = 0; o < 2; ++o)
#pragma unroll
        for (int t = 0; t < 8; ++t)
          F[(2 + o) * 8 + t] = (double)velb[o]
              + (double)velw[o * 2 + 0] * (double)vr[(0 + t) * N_PED + node]
              + (double)velw[o * 2 + 1] * (double)vr[(8 + t) * N_PED + node];
      for (int o = half * 8; o < half * 8 + 8; ++o) {
        double s = 0.0;
#pragma unroll
        for (int k = 0; k < 32; ++k) s += (double)g1w[o * 32 + k] * F[k];
        if (isrow) Arow[o][job - 64] = s;
        else Acol[o][job] = s;
      }
    }
  }
  __syncthreads();

  // ---- effective MLP params (uniform, exact reference ordering) ----
  double w2[16], b1[16];
  const double inv_std = 1.0 / sqrt(1.0 + 1e-5);
#pragma unroll
  for (int o = 0; o < 16; ++o) {
    w2[o] = (double)g2w[o] * inv_std * (double)gam[o];
    b1[o] = (double)g1b[o];
  }
  double c0 = (double)g2b[0];
#pragma unroll
  for (int o = 0; o < 16; ++o) c0 += (double)g2w[o] * (double)bet[o];

  int w = tid >> 6, lane = tid & 63;
  int c = J * 64 + lane;
  double Ac[16];
#pragma unroll
  for (int o = 0; o < 16; ++o) Ac[o] = Acol[o][lane];

  double x1v[4], x2v[4];
#pragma unroll
  for (int q = 0; q < 4; ++q) {
    int rr = w * 4 + q;
    double x1 = 0.0, x2 = 0.0;
#pragma unroll
    for (int o = 0; o < 16; ++o) {
      double Av = (I == J) ? Acol[o][chunk * 16 + rr] : Arow[o][rr];
      double s = Av - Ac[o];
      x1 += w2[o] * fmax(s + b1[o], 0.0);
      x2 += w2[o] * fmax(b1[o] - s, 0.0);
    }
    x1v[q] = x1 + c0;
    x2v[q] = x2 + c0;
  }
  double e1[4], e2[4];
#pragma unroll
  for (int q = 0; q < 4; ++q) { e1[q] = exp(x1v[q]); e2[q] = exp(x2v[q]); }
#pragma unroll
  for (int q = 0; q < 4; ++q) {
    int rr = w * 4 + q;
    int r = I * 64 + chunk * 16 + rr;
    double dist = 0.5 * (e1[q] + e2[q]);
    bool bit = (c < r) && (dist <= 1.0);
    unsigned long long word = __ballot(bit ? 1 : 0);
    if (lane == 0) {
      roww[rr] = word;
      rowmaxT[J * N_PED + r] =
          word ? (J * 64 + 63 - __clzll((long long)word)) : -1;
    }
  }
  __syncthreads();

  if (tid < 64) {  // transpose 16 rows x 64 cols -> u16 per col
    unsigned m = 0;
#pragma unroll
    for (int rr = 0; rr < 16; ++rr)
      m |= (unsigned)((roww[rr] >> tid) & 1ull) << rr;
    adjT16[(J * 64 + tid) * 48 + I * 4 + chunk] = (unsigned short)m;
  }
}

// K345: fused grouping + pooling + epilogue. One BLOCK per node n (768
// blocks, 256 threads). Labels recomputed redundantly per block (rank step
// dropped — pooling only needs membership lab[m]==lab[n]):
//   v0[m]   = rowcm[m] >= 0 ? rowcm[m] : m
//   succ(m) = first set bit in column v0[m] strictly below row m (self if none)
//   lab(m)  = v0 at the forest root, via 10 pointer-jump rounds in LDS.
// NEW pooling: wave w owns channels 4w..4w+3 -> 4 f32 accumulators + cnt per
// thread (VGPR-resident; the old s[16] layout got 28 VGPRs allocated ->
// scratch-demoted accumulators, the R9/R10 latency sink). Butterfly-reduce 5
// values, combine via a 17-float LDS slab, wave 0 emits the 60 outputs.
__global__ __launch_bounds__(256) void k345(
    const unsigned long long* __restrict__ adjT,
    const int* __restrict__ rowmaxT, const float* __restrict__ vrel,
    const float* __restrict__ wt, const float* __restrict__ wc,
    float* __restrict__ out) {
  __shared__ int nxtA[N_PED], nxtB[N_PED], valL[N_PED], labL[N_PED];
  __shared__ float poolsh[17];
  const int n = blockIdx.x;
  const int tid = threadIdx.x;
  const int w = tid >> 6, lane = tid & 63;

  // --- labels (redundant per block) ---
#pragma unroll
  for (int q = 0; q < 3; ++q) {
    int m = q * 256 + tid;
    int cm = -1;
#pragma unroll
    for (int j = 0; j < NW; ++j) {
      int t = rowmaxT[j * N_PED + m];
      cm = t > cm ? t : cm;
    }
    int v0 = (cm >= 0) ? cm : m;
    valL[m] = v0;
    int succ = m;
    int j = m >> 6, rl = m & 63;
    unsigned long long w0 = (adjT[v0 * NW + j] >> rl) >> 1;
    if (w0) {
      succ = m + __ffsll(w0);
    } else {
      for (++j; j < NW; ++j) {
        unsigned long long ww = adjT[v0 * NW + j];
        if (ww) { succ = j * 64 + __ffsll(ww) - 1; break; }
      }
    }
    nxtA[m] = succ;
  }
  __syncthreads();

  int* src = nxtA;
  int* dst = nxtB;
#pragma unroll
  for (int it = 0; it < 10; ++it) {  // 2^10 >= 767
#pragma unroll
    for (int q = 0; q < 3; ++q) {
      int m = q * 256 + tid;
      dst[m] = src[src[m]];
    }
    __syncthreads();
    int* t = src; src = dst; dst = t;
  }
#pragma unroll
  for (int q = 0; q < 3; ++q) {
    int m = q * 256 + tid;
    labL[m] = valL[src[m]];
  }
  __syncthreads();

  const int gl = labL[n];  // this block's group label (uniform)

  // --- pooling: wave w -> channels 4w..4w+3; 12 iters x 64 lanes ---
  const int ct0 = w * 4;
  float s0 = 0.f, s1 = 0.f, s2 = 0.f, s3 = 0.f;
  int cnt = 0;
#pragma unroll
  for (int k = 0; k < NW; ++k) {
    int m = k * 64 + lane;
    bool mem = (labL[m] == gl);
    cnt += mem ? 1 : 0;
    float v0 = vrel[(ct0 + 0) * N_PED + m];
    float v1 = vrel[(ct0 + 1) * N_PED + m];
    float v2 = vrel[(ct0 + 2) * N_PED + m];
    float v3 = vrel[(ct0 + 3) * N_PED + m];
    s0 += mem ? v0 : 0.f;
    s1 += mem ? v1 : 0.f;
    s2 += mem ? v2 : 0.f;
    s3 += mem ? v3 : 0.f;
  }
#pragma unroll
  for (int d = 1; d < 64; d <<= 1) {
    cnt += __shfl_xor(cnt, d);
    s0 += __shfl_xor(s0, d);
    s1 += __shfl_xor(s1, d);
    s2 += __shfl_xor(s2, d);
    s3 += __shfl_xor(s3, d);
  }
  if (lane == 0) {
    poolsh[ct0 + 0] = s0;
    poolsh[ct0 + 1] = s1;
    poolsh[ct0 + 2] = s2;
    poolsh[ct0 + 3] = s3;
    if (w == 0) poolsh[16] = (float)cnt;
  }
  __syncthreads();

  // --- epilogue: wave 0, lanes 0..59 emit the 60 outputs of node n ---
  if (w == 0) {
    float cmax = fmaxf(poolsh[16], 1.0f);
    float pool[16];
#pragma unroll
    for (int ct = 0; ct < 16; ++ct) pool[ct] = poolsh[ct] / cmax;

    if (lane < 60) {
      int o = lane / 12, p = lane % 12;
      float v1 = 0.f, v2 = 0.f;
#pragma unroll
      for (int c = 0; c < 2; ++c) {
        float u1 = 0.f, u2 = 0.f;
#pragma unroll
        for (int t = 0; t < 8; ++t) {
          float wtv = wt[t * 12 + p];
          u1 += wtv * vrel[(c * 8 + t) * N_PED + n];
          u2 += wtv * pool[c * 8 + t];
        }
        float wcv = wc[c * 5 + o];
        v1 += wcv * u1;
        v2 += wcv * u2;
      }
      out[(o * 12 + p) * N_PED + n] = (v1 + v2 + v1) / 3.0f;
    }
  }
}

extern "C" void kernel_launch(void* const* d_in, const int* in_sizes, int n_in,
                              void* d_out, int out_size, void* d_ws, size_t ws_size,
                              hipStream_t stream) {
  const float* va   = (const float*)d_in[0];
  const float* vr   = (const float*)d_in[1];
  const float* velw = (const float*)d_in[2];
  const float* velb = (const float*)d_in[3];
  const float* g1w  = (const float*)d_in[4];
  const float* g1b  = (const float*)d_in[5];
  const float* gam  = (const float*)d_in[6];
  const float* bet  = (const float*)d_in[7];
  const float* g2w  = (const float*)d_in[8];
  const float* g2b  = (const float*)d_in[9];
  const float* wt   = (const float*)d_in[10];
  const float* wc   = (const float*)d_in[11];
  float* out = (float*)d_out;

  char* ws = (char*)d_ws;
  unsigned short* adjT16 = (unsigned short*)(ws + 0);
  unsigned long long* adjT = (unsigned long long*)(ws + 0);
  int* rowmaxT = (int*)(ws + 73728);

  kb<<<576, 256, 0, stream>>>(va, vr, velw, velb, g1w, g1b, gam, bet, g2w, g2b,
                              adjT16, rowmaxT);
  k345<<<768, 256, 0, stream>>>(adjT, rowmaxT, vr, wt, wc, out);
}

// Round 14
// 24.959 us; speedup vs baseline: 1.8233x; 1.0114x over previous
//
#include <hip/hip_runtime.h>
#include <math.h>

#define N_PED 768
#define NW 12  // 768/64 u64 words per adjacency column

// ---------------- ws layout (bytes) ----------------
// adjT16  : [768*48] u16  @ 0       (73728)  column-major bits, 16-bit row-chunks
//           u64 view: word (c, I) at adjT[c*12+I]; upper tiles (I<J) unwritten
//           (proved unread: succ scan only touches words I >= J)
// rowmaxT : [12][768] int @ 73728   (36864)  per-tile row max col (or -1)

// KB: fused per-node features + pairwise dist + bit-transpose.
// Block = (tile I,J; row-chunk of 16 rows). Upper tiles (I<J): only the
// rowmaxT = -1 fills are needed. Compute blocks: recompute A (f64, exact
// reference ordering) for the 64 col + 16 row nodes in LDS, then 4 waves x
// 4 rows of pair evaluation; 8 dot-products first, then 8 independent f64
// exps back-to-back (ILP covers exp latency), then 4 ballots.
__global__ __launch_bounds__(256) void kb(
    const float* __restrict__ va, const float* __restrict__ vr,
    const float* __restrict__ velw, const float* __restrict__ velb,
    const float* __restrict__ g1w, const float* __restrict__ g1b,
    const float* __restrict__ gam, const float* __restrict__ bet,
    const float* __restrict__ g2w, const float* __restrict__ g2b,
    unsigned short* __restrict__ adjT16, int* __restrict__ rowmaxT) {
  int bid = blockIdx.x;
  int tile = bid >> 2, chunk = bid & 3;
  int I = tile / NW, J = tile % NW;
  int tid = threadIdx.x;
  if (I < J) {  // structurally zero; adjT words here are never read
    if (tid < 16) rowmaxT[J * N_PED + I * 64 + chunk * 16 + tid] = -1;
    return;
  }
  __shared__ double Acol[16][64];
  __shared__ double Arow[16][16];
  __shared__ unsigned long long roww[16];

  // ---- A compute: jobs 0..63 col nodes, 64..79 row nodes; 2 threads/job ----
  {
    int job = tid >> 1, half = tid & 1;
    bool isrow = (job >= 64);
    bool active = (job < 80) && !(isrow && I == J);
    if (active) {
      int node = isrow ? (I * 64 + chunk * 16 + (job - 64)) : (J * 64 + job);
      double F[32];
#pragma unroll
      for (int cc = 0; cc < 2; ++cc)
#pragma unroll
        for (int t = 0; t < 8; ++t)
          F[cc * 8 + t] = (double)va[(cc * 8 + t) * N_PED + node];
#pragma unroll
      for (int o = 0; o < 2; ++o)
#pragma unroll
        for (int t = 0; t < 8; ++t)
          F[(2 + o) * 8 + t] = (double)velb[o]
              + (double)velw[o * 2 + 0] * (double)vr[(0 + t) * N_PED + node]
              + (double)velw[o * 2 + 1] * (double)vr[(8 + t) * N_PED + node];
      for (int o = half * 8; o < half * 8 + 8; ++o) {
        double s = 0.0;
#pragma unroll
        for (int k = 0; k < 32; ++k) s += (double)g1w[o * 32 + k] * F[k];
        if (isrow) Arow[o][job - 64] = s;
        else Acol[o][job] = s;
      }
    }
  }
  __syncthreads();

  // ---- effective MLP params (uniform, exact reference ordering) ----
  double w2[16], b1[16];
  const double inv_std = 1.0 / sqrt(1.0 + 1e-5);
#pragma unroll
  for (int o = 0; o < 16; ++o) {
    w2[o] = (double)g2w[o] * inv_std * (double)gam[o];
    b1[o] = (double)g1b[o];
  }
  double c0 = (double)g2b[0];
#pragma unroll
  for (int o = 0; o < 16; ++o) c0 += (double)g2w[o] * (double)bet[o];

  int w = tid >> 6, lane = tid & 63;
  int c = J * 64 + lane;
  double Ac[16];
#pragma unroll
  for (int o = 0; o < 16; ++o) Ac[o] = Acol[o][lane];

  double x1v[4], x2v[4];
#pragma unroll
  for (int q = 0; q < 4; ++q) {
    int rr = w * 4 + q;
    double x1 = 0.0, x2 = 0.0;
#pragma unroll
    for (int o = 0; o < 16; ++o) {
      double Av = (I == J) ? Acol[o][chunk * 16 + rr] : Arow[o][rr];
      double s = Av - Ac[o];
      x1 += w2[o] * fmax(s + b1[o], 0.0);
      x2 += w2[o] * fmax(b1[o] - s, 0.0);
    }
    x1v[q] = x1 + c0;
    x2v[q] = x2 + c0;
  }
  double e1[4], e2[4];
#pragma unroll
  for (int q = 0; q < 4; ++q) { e1[q] = exp(x1v[q]); e2[q] = exp(x2v[q]); }
#pragma unroll
  for (int q = 0; q < 4; ++q) {
    int rr = w * 4 + q;
    int r = I * 64 + chunk * 16 + rr;
    double dist = 0.5 * (e1[q] + e2[q]);
    bool bit = (c < r) && (dist <= 1.0);
    unsigned long long word = __ballot(bit ? 1 : 0);
    if (lane == 0) {
      roww[rr] = word;
      rowmaxT[J * N_PED + r] =
          word ? (J * 64 + 63 - __clzll((long long)word)) : -1;
    }
  }
  __syncthreads();

  if (tid < 64) {  // transpose 16 rows x 64 cols -> u16 per col
    unsigned m = 0;
#pragma unroll
    for (int rr = 0; rr < 16; ++rr)
      m |= (unsigned)((roww[rr] >> tid) & 1ull) << rr;
    adjT16[(J * 64 + tid) * 48 + I * 4 + chunk] = (unsigned short)m;
  }
}

// K345: fused grouping + pooling + epilogue. One BLOCK per node n (768
// blocks, 256 threads). Labels recomputed redundantly per block (rank step
// dropped — pooling only needs membership lab[m]==lab[n]):
//   v0[m]   = rowcm[m] >= 0 ? rowcm[m] : m
//   succ(m) = first set bit in column v0[m] strictly below row m (self if none)
//   lab(m)  = v0 at the forest root, via 10 pointer-jump rounds in LDS.
// NEW succ scan: the 12 column words are consecutive -> batch-load all 12
// (independent, one waitcnt), then a branchless downward cndmask scan
// (lowest qualifying word overwrites last; own-word override). Removes the
// 12-deep dependent scattered-load chain.
__global__ __launch_bounds__(256) void k345(
    const unsigned long long* __restrict__ adjT,
    const int* __restrict__ rowmaxT, const float* __restrict__ vrel,
    const float* __restrict__ wt, const float* __restrict__ wc,
    float* __restrict__ out) {
  __shared__ int nxtA[N_PED], nxtB[N_PED], valL[N_PED], labL[N_PED];
  __shared__ float poolsh[17];
  const int n = blockIdx.x;
  const int tid = threadIdx.x;
  const int w = tid >> 6, lane = tid & 63;

  // --- labels (redundant per block) ---
#pragma unroll
  for (int q = 0; q < 3; ++q) {
    int m = q * 256 + tid;
    int cm = -1;
#pragma unroll
    for (int j = 0; j < NW; ++j) {
      int t = rowmaxT[j * N_PED + m];
      cm = t > cm ? t : cm;
    }
    int v0 = (cm >= 0) ? cm : m;
    valL[m] = v0;

    // batch-load the 12 column words (consecutive), then branchless scan
    unsigned long long cw[NW];
    const unsigned long long* cp = adjT + v0 * NW;
#pragma unroll
    for (int j = 0; j < NW; ++j) cw[j] = cp[j];
    int j0 = m >> 6, rl = m & 63;
    int succ = m;
#pragma unroll
    for (int j = NW - 1; j >= 1; --j) {  // downward: lowest j wins last
      bool take = (j > j0) && (cw[j] != 0ull);
      int cand = j * 64 + (int)__ffsll(cw[j]) - 1;
      succ = take ? cand : succ;
    }
    unsigned long long w0 = (cw[j0] >> rl) >> 1;  // bits strictly above m
    succ = w0 ? (m + (int)__ffsll(w0)) : succ;
    nxtA[m] = succ;
  }
  __syncthreads();

  int* src = nxtA;
  int* dst = nxtB;
#pragma unroll
  for (int it = 0; it < 10; ++it) {  // 2^10 >= 767
#pragma unroll
    for (int q = 0; q < 3; ++q) {
      int m = q * 256 + tid;
      dst[m] = src[src[m]];
    }
    __syncthreads();
    int* t = src; src = dst; dst = t;
  }
#pragma unroll
  for (int q = 0; q < 3; ++q) {
    int m = q * 256 + tid;
    labL[m] = valL[src[m]];
  }
  __syncthreads();

  const int gl = labL[n];  // this block's group label (uniform)

  // --- pooling: wave w -> channels 4w..4w+3; 12 iters x 64 lanes ---
  const int ct0 = w * 4;
  float s0 = 0.f, s1 = 0.f, s2 = 0.f, s3 = 0.f;
  int cnt = 0;
#pragma unroll
  for (int k = 0; k < NW; ++k) {
    int m = k * 64 + lane;
    bool mem = (labL[m] == gl);
    cnt += mem ? 1 : 0;
    float v0 = vrel[(ct0 + 0) * N_PED + m];
    float v1 = vrel[(ct0 + 1) * N_PED + m];
    float v2 = vrel[(ct0 + 2) * N_PED + m];
    float v3 = vrel[(ct0 + 3) * N_PED + m];
    s0 += mem ? v0 : 0.f;
    s1 += mem ? v1 : 0.f;
    s2 += mem ? v2 : 0.f;
    s3 += mem ? v3 : 0.f;
  }
#pragma unroll
  for (int d = 1; d < 64; d <<= 1) {
    cnt += __shfl_xor(cnt, d);
    s0 += __shfl_xor(s0, d);
    s1 += __shfl_xor(s1, d);
    s2 += __shfl_xor(s2, d);
    s3 += __shfl_xor(s3, d);
  }
  if (lane == 0) {
    poolsh[ct0 + 0] = s0;
    poolsh[ct0 + 1] = s1;
    poolsh[ct0 + 2] = s2;
    poolsh[ct0 + 3] = s3;
    if (w == 0) poolsh[16] = (float)cnt;
  }
  __syncthreads();

  // --- epilogue: wave 0, lanes 0..59 emit the 60 outputs of node n ---
  if (w == 0) {
    float cmax = fmaxf(poolsh[16], 1.0f);
    float pool[16];
#pragma unroll
    for (int ct = 0; ct < 16; ++ct) pool[ct] = poolsh[ct] / cmax;

    if (lane < 60) {
      int o = lane / 12, p = lane % 12;
      float v1 = 0.f, v2 = 0.f;
#pragma unroll
      for (int c = 0; c < 2; ++c) {
        float u1 = 0.f, u2 = 0.f;
#pragma unroll
        for (int t = 0; t < 8; ++t) {
          float wtv = wt[t * 12 + p];
          u1 += wtv * vrel[(c * 8 + t) * N_PED + n];
          u2 += wtv * pool[c * 8 + t];
        }
        float wcv = wc[c * 5 + o];
        v1 += wcv * u1;
        v2 += wcv * u2;
      }
      out[(o * 12 + p) * N_PED + n] = (v1 + v2 + v1) / 3.0f;
    }
  }
}

extern "C" void kernel_launch(void* const* d_in, const int* in_sizes, int n_in,
                              void* d_out, int out_size, void* d_ws, size_t ws_size,
                              hipStream_t stream) {
  const float* va   = (const float*)d_in[0];
  const float* vr   = (const float*)d_in[1];
  const float* velw = (const float*)d_in[2];
  const float* velb = (const float*)d_in[3];
  const float* g1w  = (const float*)d_in[4];
  const float* g1b  = (const float*)d_in[5];
  const float* gam  = (const float*)d_in[6];
  const float* bet  = (const float*)d_in[7];
  const float* g2w  = (const float*)d_in[8];
  const float* g2b  = (const float*)d_in[9];
  const float* wt   = (const float*)d_in[10];
  const float* wc   = (const float*)d_in[11];
  float* out = (float*)d_out;

  char* ws = (char*)d_ws;
  unsigned short* adjT16 = (unsigned short*)(ws + 0);
  unsigned long long* adjT = (unsigned long long*)(ws + 0);
  int* rowmaxT = (int*)(ws + 73728);

  kb<<<576, 256, 0, stream>>>(va, vr, velw, velb, g1w, g1b, gam, bet, g2w, g2b,
                              adjT16, rowmaxT);
  k345<<<768, 256, 0, stream>>>(adjT, rowmaxT, vr, wt, wc, out);
}